// Round 6
// baseline (986.159 us; speedup 1.0000x reference)
//
#include <hip/hip_runtime.h>
#include <stdint.h>

// SchNet on MI355X (gfx950). R6:
//  - aggregate: channel-quartered (4 sequential passes, quarter = slowest block
//    index) -> per-pass xj working set 3.2MB fits per-XCD 4MB L2; 4 dsts/wave,
//    16 lanes x 2ch; nontemporal pk loads protect xj residency.
//  - edge_pass2: nontemporal scatter store (was 103MB writeback = 64B/edge amp).
//  - tgemm: single launch, 64-row tiles (130 blocks vs 2x33).
//  - fused dense chains (k1/chain3/chain4), f16 table, counting sort as in R5.
// Dual-dtype (bf16/f32) inputs resolved at runtime via detect_kernel.

#define NBINS 4096
#define NROWS (NBINS + 1)
#define DMAXV 8.6610f   // slightly above sqrt(75)=8.66025

typedef _Float16 half8 __attribute__((ext_vector_type(8)));
typedef _Float16 h2 __attribute__((ext_vector_type(2)));
typedef float f32x4 __attribute__((ext_vector_type(4)));

__device__ __forceinline__ float bf2f(unsigned short u) {
  union { uint32_t i; float f; } v; v.i = ((uint32_t)u) << 16; return v.f;
}
__device__ __forceinline__ unsigned short f2bf(float f) {
  union { float f; uint32_t i; } v; v.f = f;
  uint32_t u = v.i;
  return (unsigned short)((u + 0x7fffu + ((u >> 16) & 1u)) >> 16);
}
__device__ __forceinline__ float ldf(const void* p, size_t i, int isbf) {
  if (isbf) return bf2f(((const unsigned short*)p)[i]);
  return ((const float*)p)[i];
}
__device__ __forceinline__ float sspf(float x) {
  float sp = (x > 15.0f) ? x : log1pf(expf(x));
  return sp - 0.6931471805599453f;
}

// XOR-swizzled index into a [rows][K] f16 LDS tile (8-half chunks).
template <int K>
__device__ __forceinline__ int swz(int row, int hc) {
  constexpr int mask = K / 8 - 1;
  return row * K + ((((hc >> 3) ^ (row & mask)) << 3) | (hc & 7));
}

// stage pre-transposed f16 weight [M][K] from global into swizzled LDS
template <int M, int K>
__device__ __forceinline__ void stageW(_Float16* dst, const _Float16* src, int t) {
  constexpr int CH = M * K / 8;
  constexpr int mask = K / 8 - 1;
  for (int idx = t; idx < CH; idx += 256) {
    int m = idx / (K / 8), kc = idx - m * (K / 8);
    *(half8*)&dst[m * K + ((kc ^ (m & mask)) << 3)] = *(const half8*)(src + (size_t)idx * 8);
  }
}

// ---------------- dtype detection (parallel, ballot)
__global__ void detect_kernel(const unsigned short* __restrict__ emb,
                              int* __restrict__ flag) {
  int i = threadIdx.x;
  unsigned short u = emb[2 * i];
  int e = (u >> 7) & 0xFF;
  unsigned long long m = __ballot(e >= 100 && e <= 126);
  if (i == 0) *flag = (__popcll(m) >= 32) ? 1 : 0;
}

// ---------------- weight prep: transpose all GEMM weights to f16 [M][K]
// slots: 0,1 w2[i]; 2,3 lin1[i]; 4,5 lin2[i]; 6,7 lin[i]; 8 out1; 9 out2
__global__ __launch_bounds__(256) void prep_kernel(
    const void* __restrict__ w2, const void* __restrict__ lin1,
    const void* __restrict__ lin2, const void* __restrict__ linw,
    const void* __restrict__ o1w, const void* __restrict__ o2w,
    _Float16* __restrict__ Wt, const int* __restrict__ flag) {
  int isbf = *flag;
  int slot = blockIdx.y;
  const void* src; size_t off = 0; int K = 128, M = 128;
  switch (slot) {
    case 0: src = w2;   off = 0;     break;
    case 1: src = w2;   off = 16384; break;
    case 2: src = lin1; off = 0;     break;
    case 3: src = lin1; off = 16384; break;
    case 4: src = lin2; off = 0;     break;
    case 5: src = lin2; off = 16384; break;
    case 6: src = linw; off = 0;     break;
    case 7: src = linw; off = 16384; break;
    case 8: src = o1w;  M = 64;      break;
    default: src = o2w; K = 64;      break;
  }
  int t = blockIdx.x * 256 + threadIdx.x;
  if (t >= K * M) return;
  int m = t / K, k = t - m * K;
  Wt[(size_t)slot * 16384 + t] = (_Float16)ldf(src, off + (size_t)k * M + m, isbf);
}

// ---------------- table stage 1: act[i][row][h] = ssp(rbf(row)@w1 + b1), f16
__global__ __launch_bounds__(256) void act_kernel(
    const void* __restrict__ w1, const void* __restrict__ b1,
    _Float16* __restrict__ act, const int* __restrict__ flag) {
  int isbf = *flag;
  int idx = blockIdx.x * 256 + threadIdx.x;
  int hh = idx & 127;
  int row = (idx >> 7) % NROWS;
  int i = (idx >> 7) / NROWS;
  if (i >= 2) return;
  float d = (float)row * (DMAXV / (float)NBINS);
  const float delta = 10.0f / 9.0f;
  const float coeff = -0.5f / (delta * delta);
  float u = ldf(b1, i * 128 + hh, isbf);
  #pragma unroll
  for (int g = 0; g < 10; g++) {
    float off = (float)g * delta;
    float r = expf(coeff * (d - off) * (d - off));
    u += r * ldf(w1, (size_t)(i * 10 + g) * 128 + hh, isbf);
  }
  act[idx] = (_Float16)sspf(u);
}

// ---------------- table GEMM: tables = (act @ w2 + b2) * C(d); both i in one grid
__global__ __launch_bounds__(256) void tgemm_kernel(
    const _Float16* __restrict__ A0, const _Float16* __restrict__ Wt0,
    const void* __restrict__ bias,
    _Float16* __restrict__ out0, int nrows, const int* __restrict__ flag, int tb) {
  int i = blockIdx.x / tb, bx = blockIdx.x - i * tb;
  const _Float16* A = A0 + (size_t)i * NROWS * 128;
  const _Float16* Wt = Wt0 + (size_t)i * 16384;
  _Float16* out = out0 + (size_t)i * NROWS * 128;
  size_t boff = (size_t)i * 128;
  __shared__ __align__(16) _Float16 wT[128][136];
  int t = threadIdx.x;
  #pragma unroll
  for (int idx = t; idx < 2048; idx += 256) {
    int m = idx >> 4, kc = idx & 15;
    *(half8*)&wT[m][kc * 8] = *(const half8*)(Wt + (size_t)idx * 8);
  }
  __syncthreads();
  int wave = t >> 6, lane = t & 63, quad = lane >> 4, l16 = lane & 15;
  int row0 = bx * 64 + wave * 16;
  f32x4 acc0[8] = {};
  int r0 = min(row0 + l16, nrows - 1);
  const _Float16* ap0 = A + (size_t)r0 * 128;
  #pragma unroll
  for (int ks = 0; ks < 4; ks++) {
    int kb = ks * 32 + quad * 8;
    half8 a0 = *(const half8*)(ap0 + kb);
    #pragma unroll
    for (int ct = 0; ct < 8; ct++) {
      half8 b = *(const half8*)&wT[ct * 16 + l16][kb];
      acc0[ct] = __builtin_amdgcn_mfma_f32_16x16x32_f16(a0, b, acc0[ct], 0, 0, 0);
    }
  }
  int isbf = *flag;
  #pragma unroll
  for (int ct = 0; ct < 8; ct++) {
    int col = ct * 16 + l16;
    float bv = ldf(bias, boff + col, isbf);
    #pragma unroll
    for (int r = 0; r < 4; r++) {
      int row = row0 + quad * 4 + r;
      if (row < nrows) {
        float d = (float)row * (DMAXV / (float)NBINS);
        float C = 0.5f * (cosf(d * (3.14159265358979323846f / 10.0f)) + 1.0f);
        out[(size_t)row * 128 + col] = (_Float16)((acc0[ct][r] + bv) * C);
      }
    }
  }
}

// ---------------- edge pass 1: dst histogram
__global__ __launch_bounds__(256) void edge_pass1_kernel(
    const int* __restrict__ ei, int* __restrict__ count, int E) {
  int e = blockIdx.x * 256 + threadIdx.x;
  if (e >= E) return;
  int d = __builtin_nontemporal_load(ei + E + e);
  atomicAdd(&count[d], 1);
}

// ---------------- scan phase 1: per-block sums
__global__ __launch_bounds__(256) void scan1_kernel(
    const int* __restrict__ count, int* __restrict__ bsum, int n) {
  __shared__ int red[256];
  int t = threadIdx.x, i = blockIdx.x * 256 + t;
  red[t] = (i < n) ? count[i] : 0;
  __syncthreads();
  for (int s = 128; s > 0; s >>= 1) {
    if (t < s) red[t] += red[t + s];
    __syncthreads();
  }
  if (t == 0) bsum[blockIdx.x] = red[0];
}

// ---------------- scan phase 2: scan block sums (nb <= 256)
__global__ __launch_bounds__(256) void scan2_kernel(
    const int* __restrict__ bsum, int* __restrict__ bbase, int nb,
    int* __restrict__ offs_n) {
  __shared__ int sc[256];
  int t = threadIdx.x;
  int v = (t < nb) ? bsum[t] : 0;
  sc[t] = v;
  __syncthreads();
  for (int s = 1; s < 256; s <<= 1) {
    int u = (t >= s) ? sc[t - s] : 0;
    __syncthreads();
    sc[t] += u;
    __syncthreads();
  }
  if (t < nb) bbase[t] = sc[t] - v;
  if (t == 255) *offs_n = sc[255];
}

// ---------------- scan phase 3: per-block exclusive scan + base
__global__ __launch_bounds__(256) void scan3_kernel(
    const int* __restrict__ count, const int* __restrict__ bbase,
    int* __restrict__ offs, int n) {
  __shared__ int sc[256];
  int t = threadIdx.x, i = blockIdx.x * 256 + t;
  int v = (i < n) ? count[i] : 0;
  sc[t] = v;
  __syncthreads();
  for (int s = 1; s < 256; s <<= 1) {
    int u = (t >= s) ? sc[t - s] : 0;
    __syncthreads();
    sc[t] += u;
    __syncthreads();
  }
  if (i < n) offs[i] = bbase[blockIdx.x] + sc[t] - v;
}

// ---------------- edge pass 2: distance -> nearest bin, scatter (src<<13|bin)
__global__ __launch_bounds__(256) void edge_pass2_kernel(
    const int* __restrict__ ei, const void* __restrict__ pos,
    const int* __restrict__ offs, int* __restrict__ cur,
    unsigned int* __restrict__ pk, int E, const int* __restrict__ flag) {
  int isbf = *flag;
  int e = blockIdx.x * 256 + threadIdx.x;
  if (e >= E) return;
  int s = __builtin_nontemporal_load(ei + e);
  int d = __builtin_nontemporal_load(ei + E + e);
  float ax = ldf(pos, s * 3 + 0, isbf), ay = ldf(pos, s * 3 + 1, isbf), az = ldf(pos, s * 3 + 2, isbf);
  float bx = ldf(pos, d * 3 + 0, isbf), by = ldf(pos, d * 3 + 1, isbf), bz = ldf(pos, d * 3 + 2, isbf);
  float dx = ax - bx, dy = ay - by, dz = az - bz;
  float dist = sqrtf(dx * dx + dy * dy + dz * dz);
  int q = (int)(dist * ((float)NBINS / DMAXV) + 0.5f);
  if (q > NBINS) q = NBINS;
  int p = offs[d] + atomicAdd(&cur[d], 1);
  __builtin_nontemporal_store(((unsigned int)s << 13) | (unsigned int)q, pk + p);
}

// ---------------- K1: h = emb[z] (written f16); xj = h @ lin1[0]
__global__ __launch_bounds__(256, 2) void k1_kernel(
    const void* __restrict__ emb, const int* __restrict__ z,
    const _Float16* __restrict__ Wt, _Float16* __restrict__ h,
    _Float16* __restrict__ xj, int nrows, const int* __restrict__ flag) {
  __shared__ __align__(16) _Float16 wS[128 * 128];
  int t = threadIdx.x;
  int isbf = *flag;
  stageW<128, 128>(wS, Wt, t);
  __syncthreads();
  int wave = t >> 6, lane = t & 63, quad = lane >> 4, l16 = lane & 15;
  int row0 = blockIdx.x * 128 + wave * 32;
  int r0 = row0 + l16, r1 = row0 + 16 + l16;
  int z0 = z[min(r0, nrows - 1)], z1 = z[min(r1, nrows - 1)];
  f32x4 acc0[8] = {}, acc1[8] = {};
  #pragma unroll
  for (int ks = 0; ks < 4; ks++) {
    int kb = ks * 32 + quad * 8;
    half8 a0, a1;
    #pragma unroll
    for (int j = 0; j < 8; j++) {
      a0[j] = (_Float16)ldf(emb, (size_t)z0 * 128 + kb + j, isbf);
      a1[j] = (_Float16)ldf(emb, (size_t)z1 * 128 + kb + j, isbf);
    }
    if (r0 < nrows) *(half8*)(h + (size_t)r0 * 128 + kb) = a0;
    if (r1 < nrows) *(half8*)(h + (size_t)r1 * 128 + kb) = a1;
    #pragma unroll
    for (int ct = 0; ct < 8; ct++) {
      half8 b = *(const half8*)&wS[swz<128>(ct * 16 + l16, kb)];
      acc0[ct] = __builtin_amdgcn_mfma_f32_16x16x32_f16(a0, b, acc0[ct], 0, 0, 0);
      acc1[ct] = __builtin_amdgcn_mfma_f32_16x16x32_f16(a1, b, acc1[ct], 0, 0, 0);
    }
  }
  #pragma unroll
  for (int ct = 0; ct < 8; ct++) {
    int col = ct * 16 + l16;
    #pragma unroll
    for (int rt = 0; rt < 2; rt++)
      #pragma unroll
      for (int r = 0; r < 4; r++) {
        int row = row0 + rt * 16 + quad * 4 + r;
        if (row < nrows)
          xj[(size_t)row * 128 + col] = (_Float16)(rt ? acc1[ct][r] : acc0[ct][r]);
      }
  }
}

// ---------------- CFConv aggregate: channel-quartered, 4 dsts/wave x 16 lanes x 2ch
__global__ __launch_bounds__(256) void aggregate_kernel(
    const _Float16* __restrict__ xj, const _Float16* __restrict__ table,
    const unsigned int* __restrict__ pk, const int* __restrict__ offs,
    _Float16* __restrict__ agg, int n, int nxblk) {
  int q = blockIdx.x / nxblk, bx = blockIdx.x - q * nxblk;  // quarter slowest
  int wave = threadIdx.x >> 6, lane = threadIdx.x & 63;
  int sub = lane >> 4, c = lane & 15;
  int dst = bx * 16 + wave * 4 + sub;
  int cq = q * 32 + c * 2;
  int beg = 0, cnt = 0;
  if (dst < n) { beg = offs[dst]; cnt = offs[dst + 1] - beg; }
  float a0 = 0.f, a1 = 0.f;
  for (int k = 0;; k += 2) {
    bool p0 = k < cnt, p1 = (k + 1) < cnt;
    if (!__any(p0)) break;
    if (p0) {
      unsigned int v = __builtin_nontemporal_load(pk + beg + k);
      h2 tv = *(const h2*)(table + ((size_t)(v & 8191u) << 7) + cq);
      h2 xv = *(const h2*)(xj + ((size_t)(v >> 13) << 7) + cq);
      a0 += (float)xv.x * (float)tv.x;
      a1 += (float)xv.y * (float)tv.y;
    }
    if (p1) {
      unsigned int v = __builtin_nontemporal_load(pk + beg + k + 1);
      h2 tv = *(const h2*)(table + ((size_t)(v & 8191u) << 7) + cq);
      h2 xv = *(const h2*)(xj + ((size_t)(v >> 13) << 7) + cq);
      a0 += (float)xv.x * (float)tv.x;
      a1 += (float)xv.y * (float)tv.y;
    }
  }
  if (dst < n) {
    h2 o; o.x = (_Float16)a0; o.y = (_Float16)a1;
    *(h2*)(agg + ((size_t)dst << 7) + cq) = o;
  }
}

// ---------------- K2: x=ssp(agg@lin2+b); h+=x@lin+b (in place); xj=h@lin1'
__global__ __launch_bounds__(256, 2) void chain3_kernel(
    const _Float16* __restrict__ aggb, _Float16* __restrict__ h,
    const _Float16* __restrict__ WtA, const _Float16* __restrict__ WtB,
    const _Float16* __restrict__ WtC,
    const void* __restrict__ bA, size_t bAo, const void* __restrict__ bB, size_t bBo,
    _Float16* __restrict__ xj, int nrows, const int* __restrict__ flag) {
  __shared__ __align__(16) _Float16 wS[128 * 128];
  __shared__ __align__(16) _Float16 tr[128 * 128];
  int t = threadIdx.x;
  int isbf = *flag;
  int wave = t >> 6, lane = t & 63, quad = lane >> 4, l16 = lane & 15;
  int row0 = blockIdx.x * 128 + wave * 32;
  int wrow = wave * 32;
  int lr0 = wrow + l16, lr1 = wrow + 16 + l16;

  stageW<128, 128>(wS, WtA, t);
  __syncthreads();
  {
    int r0 = min(row0 + l16, nrows - 1), r1 = min(row0 + 16 + l16, nrows - 1);
    const _Float16* ap0 = aggb + (size_t)r0 * 128;
    const _Float16* ap1 = aggb + (size_t)r1 * 128;
    f32x4 acc0[8] = {}, acc1[8] = {};
    #pragma unroll
    for (int ks = 0; ks < 4; ks++) {
      int kb = ks * 32 + quad * 8;
      half8 a0 = *(const half8*)(ap0 + kb);
      half8 a1 = *(const half8*)(ap1 + kb);
      #pragma unroll
      for (int ct = 0; ct < 8; ct++) {
        half8 b = *(const half8*)&wS[swz<128>(ct * 16 + l16, kb)];
        acc0[ct] = __builtin_amdgcn_mfma_f32_16x16x32_f16(a0, b, acc0[ct], 0, 0, 0);
        acc1[ct] = __builtin_amdgcn_mfma_f32_16x16x32_f16(a1, b, acc1[ct], 0, 0, 0);
      }
    }
    #pragma unroll
    for (int ct = 0; ct < 8; ct++) {
      int col = ct * 16 + l16;
      float bv = ldf(bA, bAo + col, isbf);
      #pragma unroll
      for (int rt = 0; rt < 2; rt++)
        #pragma unroll
        for (int r = 0; r < 4; r++)
          tr[swz<128>(wrow + rt * 16 + quad * 4 + r, col)] =
              (_Float16)sspf((rt ? acc1[ct][r] : acc0[ct][r]) + bv);
    }
  }
  __syncthreads();
  stageW<128, 128>(wS, WtB, t);
  __syncthreads();
  {
    f32x4 acc0[8] = {}, acc1[8] = {};
    #pragma unroll
    for (int ks = 0; ks < 4; ks++) {
      int kb = ks * 32 + quad * 8;
      half8 a0 = *(const half8*)&tr[swz<128>(lr0, kb)];
      half8 a1 = *(const half8*)&tr[swz<128>(lr1, kb)];
      #pragma unroll
      for (int ct = 0; ct < 8; ct++) {
        half8 b = *(const half8*)&wS[swz<128>(ct * 16 + l16, kb)];
        acc0[ct] = __builtin_amdgcn_mfma_f32_16x16x32_f16(a0, b, acc0[ct], 0, 0, 0);
        acc1[ct] = __builtin_amdgcn_mfma_f32_16x16x32_f16(a1, b, acc1[ct], 0, 0, 0);
      }
    }
    #pragma unroll
    for (int ct = 0; ct < 8; ct++) {
      int col = ct * 16 + l16;
      float bv = ldf(bB, bBo + col, isbf);
      #pragma unroll
      for (int rt = 0; rt < 2; rt++)
        #pragma unroll
        for (int r = 0; r < 4; r++) {
          int row = row0 + rt * 16 + quad * 4 + r;
          float v = (rt ? acc1[ct][r] : acc0[ct][r]) + bv;
          if (row < nrows) {
            size_t idx = (size_t)row * 128 + col;
            v += (float)h[idx];
            h[idx] = (_Float16)v;
          }
          tr[swz<128>(wrow + rt * 16 + quad * 4 + r, col)] = (_Float16)v;
        }
    }
  }
  __syncthreads();
  stageW<128, 128>(wS, WtC, t);
  __syncthreads();
  {
    f32x4 acc0[8] = {}, acc1[8] = {};
    #pragma unroll
    for (int ks = 0; ks < 4; ks++) {
      int kb = ks * 32 + quad * 8;
      half8 a0 = *(const half8*)&tr[swz<128>(lr0, kb)];
      half8 a1 = *(const half8*)&tr[swz<128>(lr1, kb)];
      #pragma unroll
      for (int ct = 0; ct < 8; ct++) {
        half8 b = *(const half8*)&wS[swz<128>(ct * 16 + l16, kb)];
        acc0[ct] = __builtin_amdgcn_mfma_f32_16x16x32_f16(a0, b, acc0[ct], 0, 0, 0);
        acc1[ct] = __builtin_amdgcn_mfma_f32_16x16x32_f16(a1, b, acc1[ct], 0, 0, 0);
      }
    }
    #pragma unroll
    for (int ct = 0; ct < 8; ct++) {
      int col = ct * 16 + l16;
      #pragma unroll
      for (int rt = 0; rt < 2; rt++)
        #pragma unroll
        for (int r = 0; r < 4; r++) {
          int row = row0 + rt * 16 + quad * 4 + r;
          if (row < nrows)
            xj[(size_t)row * 128 + col] = (_Float16)(rt ? acc1[ct][r] : acc0[ct][r]);
        }
    }
  }
}

// ---------------- K3: x=ssp(agg@lin2+b); h2=h+x@lin+b; t1=ssp(h2@o1+b); t2=t1@o2+b
__global__ __launch_bounds__(256, 2) void chain4_kernel(
    const _Float16* __restrict__ aggb, const _Float16* __restrict__ h,
    const _Float16* __restrict__ WtA, const _Float16* __restrict__ WtB,
    const _Float16* __restrict__ WtC, const _Float16* __restrict__ WtD,
    const void* __restrict__ bA, size_t bAo, const void* __restrict__ bB, size_t bBo,
    const void* __restrict__ bC, const void* __restrict__ bD,
    _Float16* __restrict__ t2, int nrows, const int* __restrict__ flag) {
  __shared__ __align__(16) _Float16 wS[128 * 128];
  __shared__ __align__(16) _Float16 tr[128 * 128];
  int t = threadIdx.x;
  int isbf = *flag;
  int wave = t >> 6, lane = t & 63, quad = lane >> 4, l16 = lane & 15;
  int row0 = blockIdx.x * 128 + wave * 32;
  int wrow = wave * 32;
  int lr0 = wrow + l16, lr1 = wrow + 16 + l16;

  stageW<128, 128>(wS, WtA, t);
  __syncthreads();
  {
    int r0 = min(row0 + l16, nrows - 1), r1 = min(row0 + 16 + l16, nrows - 1);
    const _Float16* ap0 = aggb + (size_t)r0 * 128;
    const _Float16* ap1 = aggb + (size_t)r1 * 128;
    f32x4 acc0[8] = {}, acc1[8] = {};
    #pragma unroll
    for (int ks = 0; ks < 4; ks++) {
      int kb = ks * 32 + quad * 8;
      half8 a0 = *(const half8*)(ap0 + kb);
      half8 a1 = *(const half8*)(ap1 + kb);
      #pragma unroll
      for (int ct = 0; ct < 8; ct++) {
        half8 b = *(const half8*)&wS[swz<128>(ct * 16 + l16, kb)];
        acc0[ct] = __builtin_amdgcn_mfma_f32_16x16x32_f16(a0, b, acc0[ct], 0, 0, 0);
        acc1[ct] = __builtin_amdgcn_mfma_f32_16x16x32_f16(a1, b, acc1[ct], 0, 0, 0);
      }
    }
    #pragma unroll
    for (int ct = 0; ct < 8; ct++) {
      int col = ct * 16 + l16;
      float bv = ldf(bA, bAo + col, isbf);
      #pragma unroll
      for (int rt = 0; rt < 2; rt++)
        #pragma unroll
        for (int r = 0; r < 4; r++)
          tr[swz<128>(wrow + rt * 16 + quad * 4 + r, col)] =
              (_Float16)sspf((rt ? acc1[ct][r] : acc0[ct][r]) + bv);
    }
  }
  __syncthreads();
  stageW<128, 128>(wS, WtB, t);
  __syncthreads();
  {
    f32x4 acc0[8] = {}, acc1[8] = {};
    #pragma unroll
    for (int ks = 0; ks < 4; ks++) {
      int kb = ks * 32 + quad * 8;
      half8 a0 = *(const half8*)&tr[swz<128>(lr0, kb)];
      half8 a1 = *(const half8*)&tr[swz<128>(lr1, kb)];
      #pragma unroll
      for (int ct = 0; ct < 8; ct++) {
        half8 b = *(const half8*)&wS[swz<128>(ct * 16 + l16, kb)];
        acc0[ct] = __builtin_amdgcn_mfma_f32_16x16x32_f16(a0, b, acc0[ct], 0, 0, 0);
        acc1[ct] = __builtin_amdgcn_mfma_f32_16x16x32_f16(a1, b, acc1[ct], 0, 0, 0);
      }
    }
    #pragma unroll
    for (int ct = 0; ct < 8; ct++) {
      int col = ct * 16 + l16;
      float bv = ldf(bB, bBo + col, isbf);
      #pragma unroll
      for (int rt = 0; rt < 2; rt++)
        #pragma unroll
        for (int r = 0; r < 4; r++) {
          int row = row0 + rt * 16 + quad * 4 + r;
          float v = (rt ? acc1[ct][r] : acc0[ct][r]) + bv;
          if (row < nrows) v += (float)h[(size_t)row * 128 + col];
          tr[swz<128>(wrow + rt * 16 + quad * 4 + r, col)] = (_Float16)v;
        }
    }
  }
  __syncthreads();
  stageW<64, 128>(wS, WtC, t);
  __syncthreads();
  {
    f32x4 acc0[4] = {}, acc1[4] = {};
    #pragma unroll
    for (int ks = 0; ks < 4; ks++) {
      int kb = ks * 32 + quad * 8;
      half8 a0 = *(const half8*)&tr[swz<128>(lr0, kb)];
      half8 a1 = *(const half8*)&tr[swz<128>(lr1, kb)];
      #pragma unroll
      for (int ct = 0; ct < 4; ct++) {
        half8 b = *(const half8*)&wS[swz<128>(ct * 16 + l16, kb)];
        acc0[ct] = __builtin_amdgcn_mfma_f32_16x16x32_f16(a0, b, acc0[ct], 0, 0, 0);
        acc1[ct] = __builtin_amdgcn_mfma_f32_16x16x32_f16(a1, b, acc1[ct], 0, 0, 0);
      }
    }
    #pragma unroll
    for (int ct = 0; ct < 4; ct++) {
      int col = ct * 16 + l16;
      float bv = ldf(bC, col, isbf);
      #pragma unroll
      for (int rt = 0; rt < 2; rt++)
        #pragma unroll
        for (int r = 0; r < 4; r++)
          tr[swz<128>(wrow + rt * 16 + quad * 4 + r, col)] =
              (_Float16)sspf((rt ? acc1[ct][r] : acc0[ct][r]) + bv);
    }
  }
  __syncthreads();
  stageW<128, 64>(wS, WtD, t);
  __syncthreads();
  {
    f32x4 acc0[8] = {}, acc1[8] = {};
    #pragma unroll
    for (int ks = 0; ks < 2; ks++) {
      int kb = ks * 32 + quad * 8;
      half8 a0 = *(const half8*)&tr[swz<128>(lr0, kb)];
      half8 a1 = *(const half8*)&tr[swz<128>(lr1, kb)];
      #pragma unroll
      for (int ct = 0; ct < 8; ct++) {
        half8 b = *(const half8*)&wS[swz<64>(ct * 16 + l16, kb)];
        acc0[ct] = __builtin_amdgcn_mfma_f32_16x16x32_f16(a0, b, acc0[ct], 0, 0, 0);
        acc1[ct] = __builtin_amdgcn_mfma_f32_16x16x32_f16(a1, b, acc1[ct], 0, 0, 0);
      }
    }
    #pragma unroll
    for (int ct = 0; ct < 8; ct++) {
      int col = ct * 16 + l16;
      float bv = ldf(bD, col, isbf);
      #pragma unroll
      for (int rt = 0; rt < 2; rt++)
        #pragma unroll
        for (int r = 0; r < 4; r++) {
          int row = row0 + rt * 16 + quad * 4 + r;
          if (row < nrows)
            t2[(size_t)row * 128 + col] = (_Float16)((rt ? acc1[ct][r] : acc0[ct][r]) + bv);
        }
    }
  }
}

// ---------------- batch pooling (batch sorted)
__global__ __launch_bounds__(128) void pool_kernel(
    const _Float16* __restrict__ t2, const int* __restrict__ batch,
    float* __restrict__ pooled, int n) {
  int c = threadIdx.x;
  int r0 = blockIdx.x * 128, r1 = min(r0 + 128, n);
  float acc = 0.f;
  int cur = batch[r0];
  for (int r = r0; r < r1; r++) {
    int b = batch[r];
    if (b != cur) { atomicAdd(&pooled[cur * 128 + c], acc); acc = 0.f; cur = b; }
    acc += (float)t2[(size_t)r * 128 + c];
  }
  atomicAdd(&pooled[cur * 128 + c], acc);
}

// ---------------- final: out[B,4] = pooled @ pred_w + pred_b
__global__ __launch_bounds__(256) void final_kernel(
    const float* __restrict__ pooled, const void* __restrict__ pw,
    const void* __restrict__ pb, void* __restrict__ out,
    int total, const int* __restrict__ flag) {
  int isbf = *flag;
  int t = threadIdx.x;
  if (t >= total) return;
  int b = t >> 2, j = t & 3;
  float s = ldf(pb, j, isbf);
  for (int k = 0; k < 128; k++) s += pooled[b * 128 + k] * ldf(pw, k * 4 + j, isbf);
  if (isbf) ((unsigned short*)out)[t] = f2bf(s);
  else      ((float*)out)[t] = s;
}

extern "C" void kernel_launch(void* const* d_in, const int* in_sizes, int n_in,
                              void* d_out, int out_size, void* d_ws, size_t ws_size,
                              hipStream_t stream) {
  const int* z    = (const int*)d_in[0];
  const void* pos = d_in[1];
  const int* batch = (const int*)d_in[2];
  const int* ei   = (const int*)d_in[3];
  const void* emb  = d_in[4];
  const void* w1   = d_in[5];
  const void* b1   = d_in[6];
  const void* w2   = d_in[7];
  const void* b2   = d_in[8];
  const void* lin1 = d_in[9];
  const void* lin2 = d_in[10];
  const void* lin2b= d_in[11];
  const void* linw = d_in[12];
  const void* linb = d_in[13];
  const void* o1w  = d_in[14];
  const void* o1b  = d_in[15];
  const void* o2w  = d_in[16];
  const void* o2b  = d_in[17];
  const void* pw   = d_in[18];
  const void* pb   = d_in[19];

  int N = in_sizes[0];
  int E = in_sizes[3] / 2;
  int NBLK = (N + 255) / 256;

  char* p = (char*)d_ws;
  auto carve = [&](size_t bytes) -> void* {
    void* r = (void*)p;
    p += (bytes + 255) & ~(size_t)255;
    return r;
  };
  int*      flag   = (int*)carve(256);
  _Float16* Wt     = (_Float16*)carve((size_t)10 * 16384 * 2);
  _Float16* actb   = (_Float16*)carve((size_t)2 * NROWS * 128 * 2);
  _Float16* tables = (_Float16*)carve((size_t)2 * NROWS * 128 * 2);
  unsigned int* pk = (unsigned int*)carve((size_t)E * 4);
  int*   offs   = (int*)carve((size_t)(N + 1) * 4);
  int*   bsum   = (int*)carve((size_t)NBLK * 4);
  int*   bbase  = (int*)carve((size_t)NBLK * 4);
  char*  zbase  = p;
  int*   count  = (int*)carve((size_t)N * 4);
  int*   count2 = (int*)carve((size_t)N * 4);
  float* pooled = (float*)carve((size_t)64 * 128 * 4);
  size_t zbytes = (size_t)(p - zbase);
  _Float16* h   = (_Float16*)carve((size_t)N * 128 * 2);
  _Float16* xj  = (_Float16*)carve((size_t)N * 128 * 2);   // xj0/xj1, then t2
  _Float16* agg = (_Float16*)carve((size_t)N * 128 * 2);   // agg0/agg1

  hipMemsetAsync(zbase, 0, zbytes, stream);
  detect_kernel<<<1, 64, 0, stream>>>((const unsigned short*)emb, flag);
  prep_kernel<<<dim3(64, 10), 256, 0, stream>>>(w2, lin1, lin2, linw, o1w, o2w, Wt, flag);
  act_kernel<<<(2 * NROWS * 128 + 255) / 256, 256, 0, stream>>>(w1, b1, actb, flag);

  int tb = (NROWS + 63) / 64;
  tgemm_kernel<<<2 * tb, 256, 0, stream>>>(actb, Wt, b2, tables, NROWS, flag, tb);

  edge_pass1_kernel<<<(E + 255) / 256, 256, 0, stream>>>(ei, count, E);
  scan1_kernel<<<NBLK, 256, 0, stream>>>(count, bsum, N);
  scan2_kernel<<<1, 256, 0, stream>>>(bsum, bbase, NBLK, offs + N);
  scan3_kernel<<<NBLK, 256, 0, stream>>>(count, bbase, offs, N);
  edge_pass2_kernel<<<(E + 255) / 256, 256, 0, stream>>>(ei, pos, offs, count2, pk, E, flag);

  int gblocks = (N + 127) / 128;
  int nxblk = (N + 15) / 16;
  k1_kernel<<<gblocks, 256, 0, stream>>>(emb, z, Wt + (size_t)2 * 16384, h, xj, N, flag);
  aggregate_kernel<<<nxblk * 4, 256, 0, stream>>>(xj, tables, pk, offs, agg, N, nxblk);
  chain3_kernel<<<gblocks, 256, 0, stream>>>(
      agg, h, Wt + (size_t)4 * 16384, Wt + (size_t)6 * 16384, Wt + (size_t)3 * 16384,
      lin2b, 0, linb, 0, xj, N, flag);
  aggregate_kernel<<<nxblk * 4, 256, 0, stream>>>(
      xj, tables + (size_t)NROWS * 128, pk, offs, agg, N, nxblk);
  chain4_kernel<<<gblocks, 256, 0, stream>>>(
      agg, h, Wt + (size_t)5 * 16384, Wt + (size_t)7 * 16384,
      Wt + (size_t)8 * 16384, Wt + (size_t)9 * 16384,
      lin2b, 128, linb, 128, o1b, o2b, xj, N, flag);
  pool_kernel<<<(N + 127) / 128, 128, 0, stream>>>(xj, batch, pooled, N);
  final_kernel<<<1, 256, 0, stream>>>(pooled, pw, pb, d_out, out_size, flag);
}

// Round 7
// 634.600 us; speedup vs baseline: 1.5540x; 1.5540x over previous
//
#include <hip/hip_runtime.h>
#include <stdint.h>

// SchNet on MI355X (gfx950). R7:
//  - aggregate: REVERT to R5 full-row form (R6 channel-quartering = 2.4x regression:
//    64B quarter reads still fill 128B lines -> 2x fetch amp x4 passes; NT pk loads
//    defeated line reuse). Now: 2 dsts/wave, 32 lanes x 4ch, unroll 4 (8 loads in
//    flight), plain (temporal) loads.
//  - edge_pass2: keep nontemporal SCATTER STORE only (was 103MB partial-line
//    writeback); all loads plain.
//  - tgemm: act tile fused in (computed into LDS) -> one launch, no actb buffer.
//  - fused dense chains (k1/chain3/chain4), counting sort, pool, final as in R5/R6.
// Dual-dtype (bf16/f32) inputs resolved at runtime via detect_kernel.

#define NBINS 4096
#define NROWS (NBINS + 1)
#define DMAXV 8.6610f   // slightly above sqrt(75)=8.66025

typedef _Float16 half8 __attribute__((ext_vector_type(8)));
typedef _Float16 h4 __attribute__((ext_vector_type(4)));
typedef float f32x4 __attribute__((ext_vector_type(4)));

__device__ __forceinline__ float bf2f(unsigned short u) {
  union { uint32_t i; float f; } v; v.i = ((uint32_t)u) << 16; return v.f;
}
__device__ __forceinline__ unsigned short f2bf(float f) {
  union { float f; uint32_t i; } v; v.f = f;
  uint32_t u = v.i;
  return (unsigned short)((u + 0x7fffu + ((u >> 16) & 1u)) >> 16);
}
__device__ __forceinline__ float ldf(const void* p, size_t i, int isbf) {
  if (isbf) return bf2f(((const unsigned short*)p)[i]);
  return ((const float*)p)[i];
}
__device__ __forceinline__ float sspf(float x) {
  float sp = (x > 15.0f) ? x : log1pf(expf(x));
  return sp - 0.6931471805599453f;
}

// XOR-swizzled index into a [rows][K] f16 LDS tile (8-half chunks).
template <int K>
__device__ __forceinline__ int swz(int row, int hc) {
  constexpr int mask = K / 8 - 1;
  return row * K + ((((hc >> 3) ^ (row & mask)) << 3) | (hc & 7));
}

// stage pre-transposed f16 weight [M][K] from global into swizzled LDS
template <int M, int K>
__device__ __forceinline__ void stageW(_Float16* dst, const _Float16* src, int t) {
  constexpr int CH = M * K / 8;
  constexpr int mask = K / 8 - 1;
  for (int idx = t; idx < CH; idx += 256) {
    int m = idx / (K / 8), kc = idx - m * (K / 8);
    *(half8*)&dst[m * K + ((kc ^ (m & mask)) << 3)] = *(const half8*)(src + (size_t)idx * 8);
  }
}

// ---------------- dtype detection (parallel, ballot)
__global__ void detect_kernel(const unsigned short* __restrict__ emb,
                              int* __restrict__ flag) {
  int i = threadIdx.x;
  unsigned short u = emb[2 * i];
  int e = (u >> 7) & 0xFF;
  unsigned long long m = __ballot(e >= 100 && e <= 126);
  if (i == 0) *flag = (__popcll(m) >= 32) ? 1 : 0;
}

// ---------------- weight prep: transpose all GEMM weights to f16 [M][K]
// slots: 0,1 w2[i]; 2,3 lin1[i]; 4,5 lin2[i]; 6,7 lin[i]; 8 out1; 9 out2
__global__ __launch_bounds__(256) void prep_kernel(
    const void* __restrict__ w2, const void* __restrict__ lin1,
    const void* __restrict__ lin2, const void* __restrict__ linw,
    const void* __restrict__ o1w, const void* __restrict__ o2w,
    _Float16* __restrict__ Wt, const int* __restrict__ flag) {
  int isbf = *flag;
  int slot = blockIdx.y;
  const void* src; size_t off = 0; int K = 128, M = 128;
  switch (slot) {
    case 0: src = w2;   off = 0;     break;
    case 1: src = w2;   off = 16384; break;
    case 2: src = lin1; off = 0;     break;
    case 3: src = lin1; off = 16384; break;
    case 4: src = lin2; off = 0;     break;
    case 5: src = lin2; off = 16384; break;
    case 6: src = linw; off = 0;     break;
    case 7: src = linw; off = 16384; break;
    case 8: src = o1w;  M = 64;      break;
    default: src = o2w; K = 64;      break;
  }
  int t = blockIdx.x * 256 + threadIdx.x;
  if (t >= K * M) return;
  int m = t / K, k = t - m * K;
  Wt[(size_t)slot * 16384 + t] = (_Float16)ldf(src, off + (size_t)k * M + m, isbf);
}

// ---------------- table build (fused): act tile in LDS -> GEMM -> *C(d)
__global__ __launch_bounds__(256) void tgemm_kernel(
    const void* __restrict__ w1, const void* __restrict__ b1,
    const _Float16* __restrict__ Wt0, const void* __restrict__ b2,
    _Float16* __restrict__ out0, const int* __restrict__ flag, int tb) {
  int i = blockIdx.x / tb, bx = blockIdx.x - i * tb;
  int isbf = *flag;
  __shared__ __align__(16) _Float16 aS[64][136];
  __shared__ __align__(16) _Float16 wT[128][136];
  int t = threadIdx.x;
  const _Float16* Wt = Wt0 + (size_t)i * 16384;
  #pragma unroll
  for (int idx = t; idx < 2048; idx += 256) {
    int m = idx >> 4, kc = idx & 15;
    *(half8*)&wT[m][kc * 8] = *(const half8*)(Wt + (size_t)idx * 8);
  }
  int row0 = bx * 64;
  const float delta = 10.0f / 9.0f;
  const float coeff = -0.5f / (delta * delta);
  for (int idx = t; idx < 64 * 128; idx += 256) {
    int lr = idx >> 7, hh = idx & 127;
    int row = min(row0 + lr, NROWS - 1);
    float d = (float)row * (DMAXV / (float)NBINS);
    float u = ldf(b1, i * 128 + hh, isbf);
    #pragma unroll
    for (int g = 0; g < 10; g++) {
      float off = (float)g * delta;
      float r = expf(coeff * (d - off) * (d - off));
      u += r * ldf(w1, (size_t)(i * 10 + g) * 128 + hh, isbf);
    }
    aS[lr][hh] = (_Float16)sspf(u);
  }
  __syncthreads();
  int wave = t >> 6, lane = t & 63, quad = lane >> 4, l16 = lane & 15;
  int lrow = wave * 16 + l16;
  f32x4 acc[8] = {};
  #pragma unroll
  for (int ks = 0; ks < 4; ks++) {
    int kb = ks * 32 + quad * 8;
    half8 a = *(const half8*)&aS[lrow][kb];
    #pragma unroll
    for (int ct = 0; ct < 8; ct++) {
      half8 b = *(const half8*)&wT[ct * 16 + l16][kb];
      acc[ct] = __builtin_amdgcn_mfma_f32_16x16x32_f16(a, b, acc[ct], 0, 0, 0);
    }
  }
  _Float16* out = out0 + (size_t)i * NROWS * 128;
  size_t boff = (size_t)i * 128;
  #pragma unroll
  for (int ct = 0; ct < 8; ct++) {
    int col = ct * 16 + l16;
    float bv = ldf(b2, boff + col, isbf);
    #pragma unroll
    for (int r = 0; r < 4; r++) {
      int row = row0 + wave * 16 + quad * 4 + r;
      if (row < NROWS) {
        float d = (float)row * (DMAXV / (float)NBINS);
        float C = 0.5f * (cosf(d * (3.14159265358979323846f / 10.0f)) + 1.0f);
        out[(size_t)row * 128 + col] = (_Float16)((acc[ct][r] + bv) * C);
      }
    }
  }
}

// ---------------- edge pass 1: dst histogram
__global__ __launch_bounds__(256) void edge_pass1_kernel(
    const int* __restrict__ ei, int* __restrict__ count, int E) {
  int e = blockIdx.x * 256 + threadIdx.x;
  if (e >= E) return;
  atomicAdd(&count[ei[E + e]], 1);
}

// ---------------- scan phase 1: per-block sums
__global__ __launch_bounds__(256) void scan1_kernel(
    const int* __restrict__ count, int* __restrict__ bsum, int n) {
  __shared__ int red[256];
  int t = threadIdx.x, i = blockIdx.x * 256 + t;
  red[t] = (i < n) ? count[i] : 0;
  __syncthreads();
  for (int s = 128; s > 0; s >>= 1) {
    if (t < s) red[t] += red[t + s];
    __syncthreads();
  }
  if (t == 0) bsum[blockIdx.x] = red[0];
}

// ---------------- scan phase 2: scan block sums (nb <= 256)
__global__ __launch_bounds__(256) void scan2_kernel(
    const int* __restrict__ bsum, int* __restrict__ bbase, int nb,
    int* __restrict__ offs_n) {
  __shared__ int sc[256];
  int t = threadIdx.x;
  int v = (t < nb) ? bsum[t] : 0;
  sc[t] = v;
  __syncthreads();
  for (int s = 1; s < 256; s <<= 1) {
    int u = (t >= s) ? sc[t - s] : 0;
    __syncthreads();
    sc[t] += u;
    __syncthreads();
  }
  if (t < nb) bbase[t] = sc[t] - v;
  if (t == 255) *offs_n = sc[255];
}

// ---------------- scan phase 3: per-block exclusive scan + base
__global__ __launch_bounds__(256) void scan3_kernel(
    const int* __restrict__ count, const int* __restrict__ bbase,
    int* __restrict__ offs, int n) {
  __shared__ int sc[256];
  int t = threadIdx.x, i = blockIdx.x * 256 + t;
  int v = (i < n) ? count[i] : 0;
  sc[t] = v;
  __syncthreads();
  for (int s = 1; s < 256; s <<= 1) {
    int u = (t >= s) ? sc[t - s] : 0;
    __syncthreads();
    sc[t] += u;
    __syncthreads();
  }
  if (i < n) offs[i] = bbase[blockIdx.x] + sc[t] - v;
}

// ---------------- edge pass 2: distance -> nearest bin, scatter (src<<13|bin)
__global__ __launch_bounds__(256) void edge_pass2_kernel(
    const int* __restrict__ ei, const void* __restrict__ pos,
    const int* __restrict__ offs, int* __restrict__ cur,
    unsigned int* __restrict__ pk, int E, const int* __restrict__ flag) {
  int isbf = *flag;
  int e = blockIdx.x * 256 + threadIdx.x;
  if (e >= E) return;
  int s = ei[e], d = ei[E + e];
  float ax = ldf(pos, s * 3 + 0, isbf), ay = ldf(pos, s * 3 + 1, isbf), az = ldf(pos, s * 3 + 2, isbf);
  float bx = ldf(pos, d * 3 + 0, isbf), by = ldf(pos, d * 3 + 1, isbf), bz = ldf(pos, d * 3 + 2, isbf);
  float dx = ax - bx, dy = ay - by, dz = az - bz;
  float dist = sqrtf(dx * dx + dy * dy + dz * dz);
  int q = (int)(dist * ((float)NBINS / DMAXV) + 0.5f);
  if (q > NBINS) q = NBINS;
  int p = offs[d] + atomicAdd(&cur[d], 1);
  __builtin_nontemporal_store(((unsigned int)s << 13) | (unsigned int)q, pk + p);
}

// ---------------- K1: h = emb[z] (written f16); xj = h @ lin1[0]
__global__ __launch_bounds__(256, 2) void k1_kernel(
    const void* __restrict__ emb, const int* __restrict__ z,
    const _Float16* __restrict__ Wt, _Float16* __restrict__ h,
    _Float16* __restrict__ xj, int nrows, const int* __restrict__ flag) {
  __shared__ __align__(16) _Float16 wS[128 * 128];
  int t = threadIdx.x;
  int isbf = *flag;
  stageW<128, 128>(wS, Wt, t);
  __syncthreads();
  int wave = t >> 6, lane = t & 63, quad = lane >> 4, l16 = lane & 15;
  int row0 = blockIdx.x * 128 + wave * 32;
  int r0 = row0 + l16, r1 = row0 + 16 + l16;
  int z0 = z[min(r0, nrows - 1)], z1 = z[min(r1, nrows - 1)];
  f32x4 acc0[8] = {}, acc1[8] = {};
  #pragma unroll
  for (int ks = 0; ks < 4; ks++) {
    int kb = ks * 32 + quad * 8;
    half8 a0, a1;
    #pragma unroll
    for (int j = 0; j < 8; j++) {
      a0[j] = (_Float16)ldf(emb, (size_t)z0 * 128 + kb + j, isbf);
      a1[j] = (_Float16)ldf(emb, (size_t)z1 * 128 + kb + j, isbf);
    }
    if (r0 < nrows) *(half8*)(h + (size_t)r0 * 128 + kb) = a0;
    if (r1 < nrows) *(half8*)(h + (size_t)r1 * 128 + kb) = a1;
    #pragma unroll
    for (int ct = 0; ct < 8; ct++) {
      half8 b = *(const half8*)&wS[swz<128>(ct * 16 + l16, kb)];
      acc0[ct] = __builtin_amdgcn_mfma_f32_16x16x32_f16(a0, b, acc0[ct], 0, 0, 0);
      acc1[ct] = __builtin_amdgcn_mfma_f32_16x16x32_f16(a1, b, acc1[ct], 0, 0, 0);
    }
  }
  #pragma unroll
  for (int ct = 0; ct < 8; ct++) {
    int col = ct * 16 + l16;
    #pragma unroll
    for (int rt = 0; rt < 2; rt++)
      #pragma unroll
      for (int r = 0; r < 4; r++) {
        int row = row0 + rt * 16 + quad * 4 + r;
        if (row < nrows)
          xj[(size_t)row * 128 + col] = (_Float16)(rt ? acc1[ct][r] : acc0[ct][r]);
      }
  }
}

// ---------------- CFConv aggregate: 2 dsts/wave, 32 lanes x 4ch, unroll 4
__global__ __launch_bounds__(256) void aggregate_kernel(
    const _Float16* __restrict__ xj, const _Float16* __restrict__ table,
    const unsigned int* __restrict__ pk, const int* __restrict__ offs,
    _Float16* __restrict__ agg, int n) {
  int wave = threadIdx.x >> 6, lane = threadIdx.x & 63;
  int half = lane >> 5, l32 = lane & 31;
  int dst = blockIdx.x * 8 + wave * 2 + half;
  if (dst >= n) return;
  int beg = offs[dst], end = offs[dst + 1];
  int c4 = l32 * 4;
  float a0 = 0.f, a1 = 0.f, a2 = 0.f, a3 = 0.f;
  int e = beg;
  for (; e + 4 <= end; e += 4) {
    unsigned int v0 = pk[e], v1 = pk[e + 1], v2 = pk[e + 2], v3 = pk[e + 3];
    h4 t0 = *(const h4*)(table + ((size_t)(v0 & 8191u) << 7) + c4);
    h4 x0 = *(const h4*)(xj + ((size_t)(v0 >> 13) << 7) + c4);
    h4 t1 = *(const h4*)(table + ((size_t)(v1 & 8191u) << 7) + c4);
    h4 x1 = *(const h4*)(xj + ((size_t)(v1 >> 13) << 7) + c4);
    h4 t2 = *(const h4*)(table + ((size_t)(v2 & 8191u) << 7) + c4);
    h4 x2 = *(const h4*)(xj + ((size_t)(v2 >> 13) << 7) + c4);
    h4 t3 = *(const h4*)(table + ((size_t)(v3 & 8191u) << 7) + c4);
    h4 x3 = *(const h4*)(xj + ((size_t)(v3 >> 13) << 7) + c4);
    a0 += (float)x0[0] * (float)t0[0] + (float)x1[0] * (float)t1[0]
        + (float)x2[0] * (float)t2[0] + (float)x3[0] * (float)t3[0];
    a1 += (float)x0[1] * (float)t0[1] + (float)x1[1] * (float)t1[1]
        + (float)x2[1] * (float)t2[1] + (float)x3[1] * (float)t3[1];
    a2 += (float)x0[2] * (float)t0[2] + (float)x1[2] * (float)t1[2]
        + (float)x2[2] * (float)t2[2] + (float)x3[2] * (float)t3[2];
    a3 += (float)x0[3] * (float)t0[3] + (float)x1[3] * (float)t1[3]
        + (float)x2[3] * (float)t2[3] + (float)x3[3] * (float)t3[3];
  }
  for (; e < end; e++) {
    unsigned int v0 = pk[e];
    h4 t0 = *(const h4*)(table + ((size_t)(v0 & 8191u) << 7) + c4);
    h4 x0 = *(const h4*)(xj + ((size_t)(v0 >> 13) << 7) + c4);
    a0 += (float)x0[0] * (float)t0[0];
    a1 += (float)x0[1] * (float)t0[1];
    a2 += (float)x0[2] * (float)t0[2];
    a3 += (float)x0[3] * (float)t0[3];
  }
  h4 o; o[0] = (_Float16)a0; o[1] = (_Float16)a1; o[2] = (_Float16)a2; o[3] = (_Float16)a3;
  *(h4*)(agg + ((size_t)dst << 7) + c4) = o;
}

// ---------------- K2: x=ssp(agg@lin2+b); h+=x@lin+b (in place); xj=h@lin1'
__global__ __launch_bounds__(256, 2) void chain3_kernel(
    const _Float16* __restrict__ aggb, _Float16* __restrict__ h,
    const _Float16* __restrict__ WtA, const _Float16* __restrict__ WtB,
    const _Float16* __restrict__ WtC,
    const void* __restrict__ bA, size_t bAo, const void* __restrict__ bB, size_t bBo,
    _Float16* __restrict__ xj, int nrows, const int* __restrict__ flag) {
  __shared__ __align__(16) _Float16 wS[128 * 128];
  __shared__ __align__(16) _Float16 tr[128 * 128];
  int t = threadIdx.x;
  int isbf = *flag;
  int wave = t >> 6, lane = t & 63, quad = lane >> 4, l16 = lane & 15;
  int row0 = blockIdx.x * 128 + wave * 32;
  int wrow = wave * 32;
  int lr0 = wrow + l16, lr1 = wrow + 16 + l16;

  stageW<128, 128>(wS, WtA, t);
  __syncthreads();
  {
    int r0 = min(row0 + l16, nrows - 1), r1 = min(row0 + 16 + l16, nrows - 1);
    const _Float16* ap0 = aggb + (size_t)r0 * 128;
    const _Float16* ap1 = aggb + (size_t)r1 * 128;
    f32x4 acc0[8] = {}, acc1[8] = {};
    #pragma unroll
    for (int ks = 0; ks < 4; ks++) {
      int kb = ks * 32 + quad * 8;
      half8 a0 = *(const half8*)(ap0 + kb);
      half8 a1 = *(const half8*)(ap1 + kb);
      #pragma unroll
      for (int ct = 0; ct < 8; ct++) {
        half8 b = *(const half8*)&wS[swz<128>(ct * 16 + l16, kb)];
        acc0[ct] = __builtin_amdgcn_mfma_f32_16x16x32_f16(a0, b, acc0[ct], 0, 0, 0);
        acc1[ct] = __builtin_amdgcn_mfma_f32_16x16x32_f16(a1, b, acc1[ct], 0, 0, 0);
      }
    }
    #pragma unroll
    for (int ct = 0; ct < 8; ct++) {
      int col = ct * 16 + l16;
      float bv = ldf(bA, bAo + col, isbf);
      #pragma unroll
      for (int rt = 0; rt < 2; rt++)
        #pragma unroll
        for (int r = 0; r < 4; r++)
          tr[swz<128>(wrow + rt * 16 + quad * 4 + r, col)] =
              (_Float16)sspf((rt ? acc1[ct][r] : acc0[ct][r]) + bv);
    }
  }
  __syncthreads();
  stageW<128, 128>(wS, WtB, t);
  __syncthreads();
  {
    f32x4 acc0[8] = {}, acc1[8] = {};
    #pragma unroll
    for (int ks = 0; ks < 4; ks++) {
      int kb = ks * 32 + quad * 8;
      half8 a0 = *(const half8*)&tr[swz<128>(lr0, kb)];
      half8 a1 = *(const half8*)&tr[swz<128>(lr1, kb)];
      #pragma unroll
      for (int ct = 0; ct < 8; ct++) {
        half8 b = *(const half8*)&wS[swz<128>(ct * 16 + l16, kb)];
        acc0[ct] = __builtin_amdgcn_mfma_f32_16x16x32_f16(a0, b, acc0[ct], 0, 0, 0);
        acc1[ct] = __builtin_amdgcn_mfma_f32_16x16x32_f16(a1, b, acc1[ct], 0, 0, 0);
      }
    }
    #pragma unroll
    for (int ct = 0; ct < 8; ct++) {
      int col = ct * 16 + l16;
      float bv = ldf(bB, bBo + col, isbf);
      #pragma unroll
      for (int rt = 0; rt < 2; rt++)
        #pragma unroll
        for (int r = 0; r < 4; r++) {
          int row = row0 + rt * 16 + quad * 4 + r;
          float v = (rt ? acc1[ct][r] : acc0[ct][r]) + bv;
          if (row < nrows) {
            size_t idx = (size_t)row * 128 + col;
            v += (float)h[idx];
            h[idx] = (_Float16)v;
          }
          tr[swz<128>(wrow + rt * 16 + quad * 4 + r, col)] = (_Float16)v;
        }
    }
  }
  __syncthreads();
  stageW<128, 128>(wS, WtC, t);
  __syncthreads();
  {
    f32x4 acc0[8] = {}, acc1[8] = {};
    #pragma unroll
    for (int ks = 0; ks < 4; ks++) {
      int kb = ks * 32 + quad * 8;
      half8 a0 = *(const half8*)&tr[swz<128>(lr0, kb)];
      half8 a1 = *(const half8*)&tr[swz<128>(lr1, kb)];
      #pragma unroll
      for (int ct = 0; ct < 8; ct++) {
        half8 b = *(const half8*)&wS[swz<128>(ct * 16 + l16, kb)];
        acc0[ct] = __builtin_amdgcn_mfma_f32_16x16x32_f16(a0, b, acc0[ct], 0, 0, 0);
        acc1[ct] = __builtin_amdgcn_mfma_f32_16x16x32_f16(a1, b, acc1[ct], 0, 0, 0);
      }
    }
    #pragma unroll
    for (int ct = 0; ct < 8; ct++) {
      int col = ct * 16 + l16;
      #pragma unroll
      for (int rt = 0; rt < 2; rt++)
        #pragma unroll
        for (int r = 0; r < 4; r++) {
          int row = row0 + rt * 16 + quad * 4 + r;
          if (row < nrows)
            xj[(size_t)row * 128 + col] = (_Float16)(rt ? acc1[ct][r] : acc0[ct][r]);
        }
    }
  }
}

// ---------------- K3: x=ssp(agg@lin2+b); h2=h+x@lin+b; t1=ssp(h2@o1+b); t2=t1@o2+b
__global__ __launch_bounds__(256, 2) void chain4_kernel(
    const _Float16* __restrict__ aggb, const _Float16* __restrict__ h,
    const _Float16* __restrict__ WtA, const _Float16* __restrict__ WtB,
    const _Float16* __restrict__ WtC, const _Float16* __restrict__ WtD,
    const void* __restrict__ bA, size_t bAo, const void* __restrict__ bB, size_t bBo,
    const void* __restrict__ bC, const void* __restrict__ bD,
    _Float16* __restrict__ t2, int nrows, const int* __restrict__ flag) {
  __shared__ __align__(16) _Float16 wS[128 * 128];
  __shared__ __align__(16) _Float16 tr[128 * 128];
  int t = threadIdx.x;
  int isbf = *flag;
  int wave = t >> 6, lane = t & 63, quad = lane >> 4, l16 = lane & 15;
  int row0 = blockIdx.x * 128 + wave * 32;
  int wrow = wave * 32;
  int lr0 = wrow + l16, lr1 = wrow + 16 + l16;

  stageW<128, 128>(wS, WtA, t);
  __syncthreads();
  {
    int r0 = min(row0 + l16, nrows - 1), r1 = min(row0 + 16 + l16, nrows - 1);
    const _Float16* ap0 = aggb + (size_t)r0 * 128;
    const _Float16* ap1 = aggb + (size_t)r1 * 128;
    f32x4 acc0[8] = {}, acc1[8] = {};
    #pragma unroll
    for (int ks = 0; ks < 4; ks++) {
      int kb = ks * 32 + quad * 8;
      half8 a0 = *(const half8*)(ap0 + kb);
      half8 a1 = *(const half8*)(ap1 + kb);
      #pragma unroll
      for (int ct = 0; ct < 8; ct++) {
        half8 b = *(const half8*)&wS[swz<128>(ct * 16 + l16, kb)];
        acc0[ct] = __builtin_amdgcn_mfma_f32_16x16x32_f16(a0, b, acc0[ct], 0, 0, 0);
        acc1[ct] = __builtin_amdgcn_mfma_f32_16x16x32_f16(a1, b, acc1[ct], 0, 0, 0);
      }
    }
    #pragma unroll
    for (int ct = 0; ct < 8; ct++) {
      int col = ct * 16 + l16;
      float bv = ldf(bA, bAo + col, isbf);
      #pragma unroll
      for (int rt = 0; rt < 2; rt++)
        #pragma unroll
        for (int r = 0; r < 4; r++)
          tr[swz<128>(wrow + rt * 16 + quad * 4 + r, col)] =
              (_Float16)sspf((rt ? acc1[ct][r] : acc0[ct][r]) + bv);
    }
  }
  __syncthreads();
  stageW<128, 128>(wS, WtB, t);
  __syncthreads();
  {
    f32x4 acc0[8] = {}, acc1[8] = {};
    #pragma unroll
    for (int ks = 0; ks < 4; ks++) {
      int kb = ks * 32 + quad * 8;
      half8 a0 = *(const half8*)&tr[swz<128>(lr0, kb)];
      half8 a1 = *(const half8*)&tr[swz<128>(lr1, kb)];
      #pragma unroll
      for (int ct = 0; ct < 8; ct++) {
        half8 b = *(const half8*)&wS[swz<128>(ct * 16 + l16, kb)];
        acc0[ct] = __builtin_amdgcn_mfma_f32_16x16x32_f16(a0, b, acc0[ct], 0, 0, 0);
        acc1[ct] = __builtin_amdgcn_mfma_f32_16x16x32_f16(a1, b, acc1[ct], 0, 0, 0);
      }
    }
    #pragma unroll
    for (int ct = 0; ct < 8; ct++) {
      int col = ct * 16 + l16;
      float bv = ldf(bB, bBo + col, isbf);
      #pragma unroll
      for (int rt = 0; rt < 2; rt++)
        #pragma unroll
        for (int r = 0; r < 4; r++) {
          int row = row0 + rt * 16 + quad * 4 + r;
          float v = (rt ? acc1[ct][r] : acc0[ct][r]) + bv;
          if (row < nrows) v += (float)h[(size_t)row * 128 + col];
          tr[swz<128>(wrow + rt * 16 + quad * 4 + r, col)] = (_Float16)v;
        }
    }
  }
  __syncthreads();
  stageW<64, 128>(wS, WtC, t);
  __syncthreads();
  {
    f32x4 acc0[4] = {}, acc1[4] = {};
    #pragma unroll
    for (int ks = 0; ks < 4; ks++) {
      int kb = ks * 32 + quad * 8;
      half8 a0 = *(const half8*)&tr[swz<128>(lr0, kb)];
      half8 a1 = *(const half8*)&tr[swz<128>(lr1, kb)];
      #pragma unroll
      for (int ct = 0; ct < 4; ct++) {
        half8 b = *(const half8*)&wS[swz<128>(ct * 16 + l16, kb)];
        acc0[ct] = __builtin_amdgcn_mfma_f32_16x16x32_f16(a0, b, acc0[ct], 0, 0, 0);
        acc1[ct] = __builtin_amdgcn_mfma_f32_16x16x32_f16(a1, b, acc1[ct], 0, 0, 0);
      }
    }
    #pragma unroll
    for (int ct = 0; ct < 4; ct++) {
      int col = ct * 16 + l16;
      float bv = ldf(bC, col, isbf);
      #pragma unroll
      for (int rt = 0; rt < 2; rt++)
        #pragma unroll
        for (int r = 0; r < 4; r++)
          tr[swz<128>(wrow + rt * 16 + quad * 4 + r, col)] =
              (_Float16)sspf((rt ? acc1[ct][r] : acc0[ct][r]) + bv);
    }
  }
  __syncthreads();
  stageW<128, 64>(wS, WtD, t);
  __syncthreads();
  {
    f32x4 acc0[8] = {}, acc1[8] = {};
    #pragma unroll
    for (int ks = 0; ks < 2; ks++) {
      int kb = ks * 32 + quad * 8;
      half8 a0 = *(const half8*)&tr[swz<128>(lr0, kb)];
      half8 a1 = *(const half8*)&tr[swz<128>(lr1, kb)];
      #pragma unroll
      for (int ct = 0; ct < 8; ct++) {
        half8 b = *(const half8*)&wS[swz<64>(ct * 16 + l16, kb)];
        acc0[ct] = __builtin_amdgcn_mfma_f32_16x16x32_f16(a0, b, acc0[ct], 0, 0, 0);
        acc1[ct] = __builtin_amdgcn_mfma_f32_16x16x32_f16(a1, b, acc1[ct], 0, 0, 0);
      }
    }
    #pragma unroll
    for (int ct = 0; ct < 8; ct++) {
      int col = ct * 16 + l16;
      float bv = ldf(bD, col, isbf);
      #pragma unroll
      for (int rt = 0; rt < 2; rt++)
        #pragma unroll
        for (int r = 0; r < 4; r++) {
          int row = row0 + rt * 16 + quad * 4 + r;
          if (row < nrows)
            t2[(size_t)row * 128 + col] = (_Float16)((rt ? acc1[ct][r] : acc0[ct][r]) + bv);
        }
    }
  }
}

// ---------------- batch pooling (batch sorted)
__global__ __launch_bounds__(128) void pool_kernel(
    const _Float16* __restrict__ t2, const int* __restrict__ batch,
    float* __restrict__ pooled, int n) {
  int c = threadIdx.x;
  int r0 = blockIdx.x * 128, r1 = min(r0 + 128, n);
  float acc = 0.f;
  int cur = batch[r0];
  for (int r = r0; r < r1; r++) {
    int b = batch[r];
    if (b != cur) { atomicAdd(&pooled[cur * 128 + c], acc); acc = 0.f; cur = b; }
    acc += (float)t2[(size_t)r * 128 + c];
  }
  atomicAdd(&pooled[cur * 128 + c], acc);
}

// ---------------- final: out[B,4] = pooled @ pred_w + pred_b
__global__ __launch_bounds__(256) void final_kernel(
    const float* __restrict__ pooled, const void* __restrict__ pw,
    const void* __restrict__ pb, void* __restrict__ out,
    int total, const int* __restrict__ flag) {
  int isbf = *flag;
  int t = threadIdx.x;
  if (t >= total) return;
  int b = t >> 2, j = t & 3;
  float s = ldf(pb, j, isbf);
  for (int k = 0; k < 128; k++) s += pooled[b * 128 + k] * ldf(pw, k * 4 + j, isbf);
  if (isbf) ((unsigned short*)out)[t] = f2bf(s);
  else      ((float*)out)[t] = s;
}

extern "C" void kernel_launch(void* const* d_in, const int* in_sizes, int n_in,
                              void* d_out, int out_size, void* d_ws, size_t ws_size,
                              hipStream_t stream) {
  const int* z    = (const int*)d_in[0];
  const void* pos = d_in[1];
  const int* batch = (const int*)d_in[2];
  const int* ei   = (const int*)d_in[3];
  const void* emb  = d_in[4];
  const void* w1   = d_in[5];
  const void* b1   = d_in[6];
  const void* w2   = d_in[7];
  const void* b2   = d_in[8];
  const void* lin1 = d_in[9];
  const void* lin2 = d_in[10];
  const void* lin2b= d_in[11];
  const void* linw = d_in[12];
  const void* linb = d_in[13];
  const void* o1w  = d_in[14];
  const void* o1b  = d_in[15];
  const void* o2w  = d_in[16];
  const void* o2b  = d_in[17];
  const void* pw   = d_in[18];
  const void* pb   = d_in[19];

  int N = in_sizes[0];
  int E = in_sizes[3] / 2;
  int NBLK = (N + 255) / 256;

  char* p = (char*)d_ws;
  auto carve = [&](size_t bytes) -> void* {
    void* r = (void*)p;
    p += (bytes + 255) & ~(size_t)255;
    return r;
  };
  int*      flag   = (int*)carve(256);
  _Float16* Wt     = (_Float16*)carve((size_t)10 * 16384 * 2);
  _Float16* tables = (_Float16*)carve((size_t)2 * NROWS * 128 * 2);
  unsigned int* pk = (unsigned int*)carve((size_t)E * 4);
  int*   offs   = (int*)carve((size_t)(N + 1) * 4);
  int*   bsum   = (int*)carve((size_t)NBLK * 4);
  int*   bbase  = (int*)carve((size_t)NBLK * 4);
  char*  zbase  = p;
  int*   count  = (int*)carve((size_t)N * 4);
  int*   count2 = (int*)carve((size_t)N * 4);
  float* pooled = (float*)carve((size_t)64 * 128 * 4);
  size_t zbytes = (size_t)(p - zbase);
  _Float16* h   = (_Float16*)carve((size_t)N * 128 * 2);
  _Float16* xj  = (_Float16*)carve((size_t)N * 128 * 2);   // xj0/xj1, then t2
  _Float16* agg = (_Float16*)carve((size_t)N * 128 * 2);   // agg0/agg1

  hipMemsetAsync(zbase, 0, zbytes, stream);
  detect_kernel<<<1, 64, 0, stream>>>((const unsigned short*)emb, flag);
  prep_kernel<<<dim3(64, 10), 256, 0, stream>>>(w2, lin1, lin2, linw, o1w, o2w, Wt, flag);

  int tb = (NROWS + 63) / 64;
  tgemm_kernel<<<2 * tb, 256, 0, stream>>>(w1, b1, Wt, b2, tables, flag, tb);

  edge_pass1_kernel<<<(E + 255) / 256, 256, 0, stream>>>(ei, count, E);
  scan1_kernel<<<NBLK, 256, 0, stream>>>(count, bsum, N);
  scan2_kernel<<<1, 256, 0, stream>>>(bsum, bbase, NBLK, offs + N);
  scan3_kernel<<<NBLK, 256, 0, stream>>>(count, bbase, offs, N);
  edge_pass2_kernel<<<(E + 255) / 256, 256, 0, stream>>>(ei, pos, offs, count2, pk, E, flag);

  int gblocks = (N + 127) / 128;
  k1_kernel<<<gblocks, 256, 0, stream>>>(emb, z, Wt + (size_t)2 * 16384, h, xj, N, flag);
  aggregate_kernel<<<(N + 7) / 8, 256, 0, stream>>>(xj, tables, pk, offs, agg, N);
  chain3_kernel<<<gblocks, 256, 0, stream>>>(
      agg, h, Wt + (size_t)4 * 16384, Wt + (size_t)6 * 16384, Wt + (size_t)3 * 16384,
      lin2b, 0, linb, 0, xj, N, flag);
  aggregate_kernel<<<(N + 7) / 8, 256, 0, stream>>>(
      xj, tables + (size_t)NROWS * 128, pk, offs, agg, N);
  chain4_kernel<<<gblocks, 256, 0, stream>>>(
      agg, h, Wt + (size_t)5 * 16384, Wt + (size_t)7 * 16384,
      Wt + (size_t)8 * 16384, Wt + (size_t)9 * 16384,
      lin2b, 128, linb, 128, o1b, o2b, xj, N, flag);
  pool_kernel<<<(N + 127) / 128, 128, 0, stream>>>(xj, batch, pooled, N);
  final_kernel<<<1, 256, 0, stream>>>(pooled, pw, pb, d_out, out_size, flag);
}